// Round 1
// baseline (1883.567 us; speedup 1.0000x reference)
//
#include <hip/hip_runtime.h>
#include <hip/hip_bf16.h>

// Problem constants
#define BB 4
#define NN 4096
#define CC 1024
#define HH 16
#define DD 64
#define TOKENS (BB * NN)          // 16384
#define QKV_LD 3072               // 3*C

// ---------------------------------------------------------------------------
// Tiled fp32 GEMM with bias: C[M,N] = A[M,K] @ B[K,N] + bias[N]
// A has row stride lda (>= K). 128x128 tile, 256 threads, 8x8 per thread.
// ---------------------------------------------------------------------------
__global__ __launch_bounds__(256) void gemm_bias_kernel(
    const float* __restrict__ A, const float* __restrict__ Bm,
    const float* __restrict__ bias, float* __restrict__ C,
    int M, int N, int K, int lda)
{
    __shared__ float As[16][128 + 4];
    __shared__ float Bs[16][128 + 4];
    const int t = threadIdx.x;
    const int row0 = blockIdx.y * 128;
    const int col0 = blockIdx.x * 128;
    const int tx = t & 15;        // 0..15 -> col group
    const int ty = t >> 4;        // 0..15 -> row group

    float acc[8][8];
#pragma unroll
    for (int i = 0; i < 8; i++)
#pragma unroll
        for (int j = 0; j < 8; j++) acc[i][j] = 0.0f;

    for (int k0 = 0; k0 < K; k0 += 16) {
        // Load A tile (128 rows x 16 cols) as float4: 512 float4, 2/thread.
#pragma unroll
        for (int l = 0; l < 2; l++) {
            int idx = t + l * 256;            // 0..511
            int m   = idx >> 2;               // 0..127
            int kk  = (idx & 3) * 4;          // 0,4,8,12
            float4 av = *reinterpret_cast<const float4*>(
                &A[(size_t)(row0 + m) * lda + k0 + kk]);
            As[kk + 0][m] = av.x;
            As[kk + 1][m] = av.y;
            As[kk + 2][m] = av.z;
            As[kk + 3][m] = av.w;
        }
        // Load B tile (16 rows x 128 cols) as float4: 512 float4, 2/thread.
#pragma unroll
        for (int l = 0; l < 2; l++) {
            int idx = t + l * 256;            // 0..511
            int kk  = idx >> 5;               // 0..15
            int n   = (idx & 31) * 4;         // 0..124
            float4 bv = *reinterpret_cast<const float4*>(
                &Bm[(size_t)(k0 + kk) * N + col0 + n]);
            *reinterpret_cast<float4*>(&Bs[kk][n]) = bv;
        }
        __syncthreads();

#pragma unroll
        for (int kk = 0; kk < 16; kk++) {
            float a[8], b[8];
            float4 a0 = *reinterpret_cast<const float4*>(&As[kk][ty * 8]);
            float4 a1 = *reinterpret_cast<const float4*>(&As[kk][ty * 8 + 4]);
            float4 b0 = *reinterpret_cast<const float4*>(&Bs[kk][tx * 8]);
            float4 b1 = *reinterpret_cast<const float4*>(&Bs[kk][tx * 8 + 4]);
            a[0] = a0.x; a[1] = a0.y; a[2] = a0.z; a[3] = a0.w;
            a[4] = a1.x; a[5] = a1.y; a[6] = a1.z; a[7] = a1.w;
            b[0] = b0.x; b[1] = b0.y; b[2] = b0.z; b[3] = b0.w;
            b[4] = b1.x; b[5] = b1.y; b[6] = b1.z; b[7] = b1.w;
#pragma unroll
            for (int i = 0; i < 8; i++)
#pragma unroll
                for (int j = 0; j < 8; j++)
                    acc[i][j] += a[i] * b[j];
        }
        __syncthreads();
    }

    // Epilogue: add bias, store.
#pragma unroll
    for (int i = 0; i < 8; i++) {
        int r = row0 + ty * 8 + i;
#pragma unroll
        for (int j = 0; j < 8; j += 4) {
            int c = col0 + tx * 8 + j;
            float4 o;
            o.x = acc[i][j + 0] + bias[c + 0];
            o.y = acc[i][j + 1] + bias[c + 1];
            o.z = acc[i][j + 2] + bias[c + 2];
            o.w = acc[i][j + 3] + bias[c + 3];
            *reinterpret_cast<float4*>(&C[(size_t)r * N + c]) = o;
        }
    }
}

// ---------------------------------------------------------------------------
// Q softmax over head_dim (64). One wave per (b,n,h) row; lane = d.
// ---------------------------------------------------------------------------
__global__ __launch_bounds__(256) void q_softmax_kernel(float* __restrict__ qkv)
{
    const int wid  = threadIdx.x >> 6;   // 0..3
    const int lane = threadIdx.x & 63;
    const long r = (long)blockIdx.x * 4 + wid;   // (b*N+n)*H + h, < 262144
    const size_t off = (size_t)(r >> 4) * QKV_LD + (size_t)(r & 15) * 64 + lane;
    float v = qkv[off];
    float m = v;
#pragma unroll
    for (int s = 32; s > 0; s >>= 1) m = fmaxf(m, __shfl_xor(m, s));
    float e = __expf(v - m);
    float sum = e;
#pragma unroll
    for (int s = 32; s > 0; s >>= 1) sum += __shfl_xor(sum, s);
    qkv[off] = e / sum;
}

// ---------------------------------------------------------------------------
// K softmax over sequence N (column softmax), two-stage.
// Stage A: per (b,h,chunk of 256 n): per-column max and sum(exp(x-max)).
// ---------------------------------------------------------------------------
__global__ __launch_bounds__(256) void ksm_partial_kernel(
    const float* __restrict__ qkv, float* __restrict__ pmax, float* __restrict__ psum)
{
    const int bh = blockIdx.x;           // 0..63
    const int ch = blockIdx.y;           // 0..15
    const int b = bh >> 4, h = bh & 15;
    const int d = threadIdx.x & 63;
    const int s = threadIdx.x >> 6;      // 0..3
    const size_t base = (size_t)b * NN * QKV_LD + CC + (size_t)h * 64 + d;
    const int n0 = ch * 256;

    __shared__ float red[4][64];

    float m = -1e30f;
    for (int i = s; i < 256; i += 4)
        m = fmaxf(m, qkv[base + (size_t)(n0 + i) * QKV_LD]);
    red[s][d] = m;
    __syncthreads();
    float cm = fmaxf(fmaxf(red[0][d], red[1][d]), fmaxf(red[2][d], red[3][d]));
    __syncthreads();

    float sum = 0.0f;
    for (int i = s; i < 256; i += 4)
        sum += __expf(qkv[base + (size_t)(n0 + i) * QKV_LD] - cm);
    red[s][d] = sum;
    __syncthreads();
    if (threadIdx.x < 64) {
        float tot = red[0][d] + red[1][d] + red[2][d] + red[3][d];
        pmax[((size_t)bh * 16 + ch) * 64 + d] = cm;
        psum[((size_t)bh * 16 + ch) * 64 + d] = tot;
    }
}

// Stage B: combine partials (recomputed per block, cheap) + normalize chunk.
__global__ __launch_bounds__(256) void ksm_norm_kernel(
    float* __restrict__ qkv, const float* __restrict__ pmax, const float* __restrict__ psum)
{
    const int bh = blockIdx.x;
    const int ch = blockIdx.y;
    const int b = bh >> 4, h = bh & 15;
    const int t = threadIdx.x;

    __shared__ float cm[64], cinv[64];
    if (t < 64) {
        float m = -1e30f;
        for (int c = 0; c < 16; c++)
            m = fmaxf(m, pmax[((size_t)bh * 16 + c) * 64 + t]);
        float sum = 0.0f;
        for (int c = 0; c < 16; c++)
            sum += psum[((size_t)bh * 16 + c) * 64 + t] *
                   __expf(pmax[((size_t)bh * 16 + c) * 64 + t] - m);
        cm[t] = m;
        cinv[t] = 1.0f / sum;
    }
    __syncthreads();

    const int d = t & 63;
    const int s = t >> 6;
    const size_t base = (size_t)b * NN * QKV_LD + CC + (size_t)h * 64 + d;
    const int n0 = ch * 256;
    for (int i = s; i < 256; i += 4) {
        size_t o = base + (size_t)(n0 + i) * QKV_LD;
        qkv[o] = __expf(qkv[o] - cm[d]) * cinv[d];
    }
}

// ---------------------------------------------------------------------------
// ctx[b,h,d,e] = sum_n K[b,h,n,d] * V[b,h,n,e]   (partial over n-chunks, atomic)
// ---------------------------------------------------------------------------
__global__ __launch_bounds__(256) void context_kernel(
    const float* __restrict__ qkv, float* __restrict__ ctx)
{
    const int bh = blockIdx.x;          // 0..63
    const int ch = blockIdx.y;          // 0..15
    const int b = bh >> 4, h = bh & 15;
    const int t = threadIdx.x;
    const int d0 = (t >> 4) * 4;
    const int e0 = (t & 15) * 4;

    __shared__ float Ks[32][68];
    __shared__ float Vs[32][68];

    float acc[4][4];
#pragma unroll
    for (int i = 0; i < 4; i++)
#pragma unroll
        for (int j = 0; j < 4; j++) acc[i][j] = 0.0f;

    const size_t baseK = (size_t)(b * NN + ch * 256) * QKV_LD + CC + (size_t)h * 64;
    const size_t baseV = baseK + CC;

    for (int n0 = 0; n0 < 256; n0 += 32) {
#pragma unroll
        for (int l = 0; l < 2; l++) {
            int idx = t + l * 256;        // 0..511
            int r = idx >> 4;             // 0..31
            int c = (idx & 15) * 4;       // 0..60
            *reinterpret_cast<float4*>(&Ks[r][c]) =
                *reinterpret_cast<const float4*>(&qkv[baseK + (size_t)(n0 + r) * QKV_LD + c]);
            *reinterpret_cast<float4*>(&Vs[r][c]) =
                *reinterpret_cast<const float4*>(&qkv[baseV + (size_t)(n0 + r) * QKV_LD + c]);
        }
        __syncthreads();
#pragma unroll 8
        for (int n = 0; n < 32; n++) {
            float4 a = *reinterpret_cast<const float4*>(&Ks[n][d0]);
            float4 v4 = *reinterpret_cast<const float4*>(&Vs[n][e0]);
            float a4[4] = {a.x, a.y, a.z, a.w};
            float b4[4] = {v4.x, v4.y, v4.z, v4.w};
#pragma unroll
            for (int i = 0; i < 4; i++)
#pragma unroll
                for (int j = 0; j < 4; j++)
                    acc[i][j] += a4[i] * b4[j];
        }
        __syncthreads();
    }

#pragma unroll
    for (int i = 0; i < 4; i++)
#pragma unroll
        for (int j = 0; j < 4; j++)
            atomicAdd(&ctx[((size_t)bh * 64 + d0 + i) * 64 + e0 + j], acc[i][j]);
}

// ---------------------------------------------------------------------------
// out2[b,n,h,e] = sum_d Q[b,h,n,d] * ctx[b,h,d,e]
// Written into the (dead) K region of qkv so proj can read it with lda=3072.
// ---------------------------------------------------------------------------
__global__ __launch_bounds__(256) void attn_out_kernel(
    float* __restrict__ qkv, const float* __restrict__ ctx)
{
    const int bh = blockIdx.x;          // 0..63
    const int nch = blockIdx.y;         // 0..63 (64 rows each)
    const int b = bh >> 4, h = bh & 15;
    const int t = threadIdx.x;

    __shared__ float Cs[64][68];
    __shared__ float Qs[64][68];

#pragma unroll
    for (int l = 0; l < 4; l++) {
        int idx = t + l * 256;          // 0..1023
        int r = idx >> 4;               // 0..63
        int c = (idx & 15) * 4;         // 0..60
        *reinterpret_cast<float4*>(&Cs[r][c]) =
            *reinterpret_cast<const float4*>(&ctx[(size_t)bh * 4096 + r * 64 + c]);
        *reinterpret_cast<float4*>(&Qs[r][c]) =
            *reinterpret_cast<const float4*>(
                &qkv[(size_t)(b * NN + nch * 64 + r) * QKV_LD + (size_t)h * 64 + c]);
    }
    __syncthreads();

    const int r0 = (t >> 4) * 4;
    const int e0 = (t & 15) * 4;
    float acc[4][4];
#pragma unroll
    for (int i = 0; i < 4; i++)
#pragma unroll
        for (int j = 0; j < 4; j++) acc[i][j] = 0.0f;

#pragma unroll 8
    for (int d = 0; d < 64; d++) {
        float a4[4];
#pragma unroll
        for (int i = 0; i < 4; i++) a4[i] = Qs[r0 + i][d];
        float4 c4 = *reinterpret_cast<const float4*>(&Cs[d][e0]);
        float b4[4] = {c4.x, c4.y, c4.z, c4.w};
#pragma unroll
        for (int i = 0; i < 4; i++)
#pragma unroll
            for (int j = 0; j < 4; j++)
                acc[i][j] += a4[i] * b4[j];
    }

#pragma unroll
    for (int i = 0; i < 4; i++) {
        size_t o = (size_t)(b * NN + nch * 64 + r0 + i) * QKV_LD + CC + (size_t)h * 64 + e0;
        float4 v;
        v.x = acc[i][0]; v.y = acc[i][1]; v.z = acc[i][2]; v.w = acc[i][3];
        *reinterpret_cast<float4*>(&qkv[o]) = v;
    }
}

// ---------------------------------------------------------------------------
extern "C" void kernel_launch(void* const* d_in, const int* in_sizes, int n_in,
                              void* d_out, int out_size, void* d_ws, size_t ws_size,
                              hipStream_t stream)
{
    const float* x      = (const float*)d_in[0];
    const float* W_qkv  = (const float*)d_in[1];
    const float* b_qkv  = (const float*)d_in[2];
    const float* W_proj = (const float*)d_in[3];
    const float* b_proj = (const float*)d_in[4];
    float* out = (float*)d_out;

    float* qkv  = (float*)d_ws;                              // [16384, 3072]
    float* ctx  = qkv + (size_t)TOKENS * QKV_LD;             // [64, 64, 64]
    float* pmax = ctx + (size_t)64 * 64 * 64;                // [64, 16, 64]
    float* psum = pmax + (size_t)64 * 16 * 64;               // [64, 16, 64]

    hipMemsetAsync(ctx, 0, (size_t)64 * 64 * 64 * sizeof(float), stream);

    // 1) QKV GEMM: [16384,1024] @ [1024,3072] + bias
    gemm_bias_kernel<<<dim3(QKV_LD / 128, TOKENS / 128), 256, 0, stream>>>(
        x, W_qkv, b_qkv, qkv, TOKENS, QKV_LD, CC, CC);

    // 2) softmax(Q) over head_dim
    q_softmax_kernel<<<(TOKENS * HH) / 4, 256, 0, stream>>>(qkv);

    // 3) softmax(K) over sequence
    ksm_partial_kernel<<<dim3(BB * HH, 16), 256, 0, stream>>>(qkv, pmax, psum);
    ksm_norm_kernel<<<dim3(BB * HH, 16), 256, 0, stream>>>(qkv, pmax, psum);

    // 4) ctx = K^T V per head
    context_kernel<<<dim3(BB * HH, 16), 256, 0, stream>>>(qkv, ctx);

    // 5) out2 = Q @ ctx  (into K region of qkv)
    attn_out_kernel<<<dim3(BB * HH, NN / 64), 256, 0, stream>>>(qkv, ctx);

    // 6) proj GEMM: [16384,1024](lda=3072) @ [1024,1024] + bias
    gemm_bias_kernel<<<dim3(CC / 128, TOKENS / 128), 256, 0, stream>>>(
        qkv + CC, W_proj, b_proj, out, TOKENS, CC, CC, QKV_LD);
}

// Round 3
// 460.989 us; speedup vs baseline: 4.0859x; 4.0859x over previous
//
#include <hip/hip_runtime.h>

// Problem constants
#define BBATCH 4
#define SEQ 4096
#define CC 1024
#define HH 16
#define DD 64
#define TOKENS 16384              // B*N
#define QKV3 3072                 // 3*C

typedef __attribute__((ext_vector_type(8))) short short8;
typedef __attribute__((ext_vector_type(4))) float floatx4;

// bf16 helpers (RNE)
__device__ __forceinline__ unsigned short f2bf(float x) {
    unsigned int u = __float_as_uint(x);
    u += 0x7fff + ((u >> 16) & 1);
    return (unsigned short)(u >> 16);
}
__device__ __forceinline__ float bf2f(unsigned short h) {
    return __uint_as_float((unsigned int)h << 16);
}

__device__ __forceinline__ void gload_lds16(const void* g, void* l) {
    __builtin_amdgcn_global_load_lds(
        (const __attribute__((address_space(1))) unsigned int*)g,
        (__attribute__((address_space(3))) unsigned int*)l, 16, 0, 0);
}

// ---------------------------------------------------------------------------
// fp32 -> bf16 convert (x)
// ---------------------------------------------------------------------------
__global__ __launch_bounds__(256) void cvt_bf16_kernel(
    const float* __restrict__ X, unsigned short* __restrict__ Y, long n4)
{
    long i = (long)blockIdx.x * 256 + threadIdx.x;
    if (i >= n4) return;
    float4 v = *reinterpret_cast<const float4*>(&X[i * 4]);
    ushort4 h;
    h.x = f2bf(v.x); h.y = f2bf(v.y); h.z = f2bf(v.z); h.w = f2bf(v.w);
    *reinterpret_cast<ushort4*>(&Y[i * 4]) = h;
}

// ---------------------------------------------------------------------------
// Transpose W[K,N] -> T[N,K] bf16. 32x32 tiles, 256 threads.
// ---------------------------------------------------------------------------
__global__ __launch_bounds__(256) void transpose_bf16_kernel(
    const float* __restrict__ W, int K, int N, unsigned short* __restrict__ T)
{
    __shared__ unsigned short Lh[32][36];
    const int k0 = blockIdx.y * 32, n0 = blockIdx.x * 32;
    const int t = threadIdx.x;
    const int r = t >> 3, c4 = (t & 7) * 4;

    float4 w = *reinterpret_cast<const float4*>(&W[(size_t)(k0 + r) * N + n0 + c4]);
    Lh[r][c4 + 0] = f2bf(w.x);
    Lh[r][c4 + 1] = f2bf(w.y);
    Lh[r][c4 + 2] = f2bf(w.z);
    Lh[r][c4 + 3] = f2bf(w.w);
    __syncthreads();

    const int rn = t >> 3, ck = (t & 7) * 4;
    ushort4 h4;
    h4.x = Lh[ck + 0][rn]; h4.y = Lh[ck + 1][rn];
    h4.z = Lh[ck + 2][rn]; h4.w = Lh[ck + 3][rn];
    *reinterpret_cast<ushort4*>(&T[(size_t)(n0 + rn) * K + k0 + ck]) = h4;
}

// ---------------------------------------------------------------------------
// bf16 MFMA GEMM (m97 structure): C[M,N] = A[M,K] @ B[K,N] + bias[N]
// A [M,lda] bf16 k-contiguous; Bt [N,ldb] bf16 k-contiguous (pre-transposed).
// 128x128 tile, BK=32, 4 waves each 64x64 (4x4 of 16x16x32 MFMA).
// MODE 0: fp32 store to Cf (ldc). MODE 1: bf16 scatter to Q/K/V (+bias).
// ---------------------------------------------------------------------------
template <int MODE>
__global__ __launch_bounds__(256) void gemm_bf16_kernel(
    const unsigned short* __restrict__ A, int lda,
    const unsigned short* __restrict__ Bt, int ldb,
    const float* __restrict__ bias,
    float* __restrict__ Cf, int ldc,
    unsigned short* __restrict__ Qo, unsigned short* __restrict__ Ko,
    unsigned short* __restrict__ Vo, int Kdim)
{
    __shared__ unsigned short As[128 * 32];
    __shared__ unsigned short Bs[128 * 32];

    const int t = threadIdx.x;
    const int wave = t >> 6, lane = t & 63;
    const int row0 = blockIdx.y * 128, col0 = blockIdx.x * 128;
    const int wm = (wave >> 1) * 64, wn = (wave & 1) * 64;

    floatx4 acc[4][4];
#pragma unroll
    for (int i = 0; i < 4; i++)
#pragma unroll
        for (int j = 0; j < 4; j++) acc[i][j] = (floatx4)0.0f;

    const int srow = lane >> 2;          // 0..15
    const int skc = (lane & 3) * 8;      // k-offset in ushorts (16B chunks)
    const int fr = lane & 15;
    const int fq = (lane >> 4) * 8;

    for (int k0 = 0; k0 < Kdim; k0 += 32) {
        __syncthreads();
#pragma unroll
        for (int l = 0; l < 2; l++) {
            const int rr = wave * 32 + l * 16;
            gload_lds16(&A[(size_t)(row0 + rr + srow) * lda + k0 + skc], &As[rr * 32]);
            gload_lds16(&Bt[(size_t)(col0 + rr + srow) * ldb + k0 + skc], &Bs[rr * 32]);
        }
        __syncthreads();

        short8 af[4], bf[4];
#pragma unroll
        for (int i = 0; i < 4; i++) {
            af[i] = *reinterpret_cast<const short8*>(&As[(wm + i * 16 + fr) * 32 + fq]);
            bf[i] = *reinterpret_cast<const short8*>(&Bs[(wn + i * 16 + fr) * 32 + fq]);
        }
#pragma unroll
        for (int i = 0; i < 4; i++)
#pragma unroll
            for (int j = 0; j < 4; j++)
                acc[i][j] = __builtin_amdgcn_mfma_f32_16x16x32_bf16(af[i], bf[j], acc[i][j], 0, 0, 0);
    }

    // C/D layout: col = lane&15, row = (lane>>4)*4 + reg  [m89-verified]
    const int cn = lane & 15, cq = (lane >> 4) * 4;
    if (MODE == 0) {
#pragma unroll
        for (int j = 0; j < 4; j++) {
            const int col = col0 + wn + j * 16 + cn;
            const float bv = bias[col];
#pragma unroll
            for (int i = 0; i < 4; i++)
#pragma unroll
                for (int r = 0; r < 4; r++) {
                    const int row = row0 + wm + i * 16 + cq + r;
                    Cf[(size_t)row * ldc + col] = acc[i][j][r] + bv;
                }
        }
    } else {
        unsigned short* outp = (blockIdx.x < 8) ? Qo : ((blockIdx.x < 16) ? Ko : Vo);
        const int f0 = col0 & 1023;
#pragma unroll
        for (int j = 0; j < 4; j++) {
            const int colg = col0 + wn + j * 16 + cn;   // bias index in [0,3072)
            const int f = f0 + wn + j * 16 + cn;        // feature in [0,1024)
            const float bv = bias[colg];
#pragma unroll
            for (int i = 0; i < 4; i++)
#pragma unroll
                for (int r = 0; r < 4; r++) {
                    const int row = row0 + wm + i * 16 + cq + r;
                    outp[(size_t)row * CC + f] = f2bf(acc[i][j][r] + bv);
                }
        }
    }
}

// ---------------------------------------------------------------------------
// Q softmax over head_dim (64), bf16 in/out. 16 lanes per head-row.
// ---------------------------------------------------------------------------
__global__ __launch_bounds__(256) void q_softmax_kernel(unsigned short* __restrict__ Q)
{
    const int t = threadIdx.x;
    const long row = (long)blockIdx.x * 16 + (t >> 4);   // (token*H + h), < 262144
    const int d4 = (t & 15) * 4;
    ushort4 hv = *reinterpret_cast<const ushort4*>(&Q[row * 64 + d4]);
    float v0 = bf2f(hv.x), v1 = bf2f(hv.y), v2 = bf2f(hv.z), v3 = bf2f(hv.w);
    float m = fmaxf(fmaxf(v0, v1), fmaxf(v2, v3));
#pragma unroll
    for (int s = 8; s > 0; s >>= 1) m = fmaxf(m, __shfl_xor(m, s));
    float e0 = __expf(v0 - m), e1 = __expf(v1 - m), e2 = __expf(v2 - m), e3 = __expf(v3 - m);
    float sum = e0 + e1 + e2 + e3;
#pragma unroll
    for (int s = 8; s > 0; s >>= 1) sum += __shfl_xor(sum, s);
    const float inv = 1.0f / sum;
    ushort4 o;
    o.x = f2bf(e0 * inv); o.y = f2bf(e1 * inv); o.z = f2bf(e2 * inv); o.w = f2bf(e3 * inv);
    *reinterpret_cast<ushort4*>(&Q[row * 64 + d4]) = o;
}

// ---------------------------------------------------------------------------
// K softmax over sequence N (column softmax), two-stage, bf16 K tensor.
// Stage A: per (b,h, 256-row chunk): per-column max and sum(exp).
// ---------------------------------------------------------------------------
__global__ __launch_bounds__(256) void ksm_partial_kernel(
    const unsigned short* __restrict__ Km, float* __restrict__ pmax, float* __restrict__ psum)
{
    const int bh = blockIdx.x, ch = blockIdx.y;
    const int b = bh >> 4, h = bh & 15;
    const int t = threadIdx.x;
    const int d4 = (t & 15) * 4, rg = t >> 4;
    const size_t base = (size_t)b * SEQ * CC + (size_t)h * 64;
    const int n0 = ch * 256;

    __shared__ float red[16][64];
    __shared__ float cmx[64];

    float m0 = -1e30f, m1 = -1e30f, m2 = -1e30f, m3 = -1e30f;
    for (int i = 0; i < 16; i++) {
        const int n = n0 + rg + i * 16;
        ushort4 hv = *reinterpret_cast<const ushort4*>(&Km[base + (size_t)n * CC + d4]);
        m0 = fmaxf(m0, bf2f(hv.x)); m1 = fmaxf(m1, bf2f(hv.y));
        m2 = fmaxf(m2, bf2f(hv.z)); m3 = fmaxf(m3, bf2f(hv.w));
    }
    red[rg][d4 + 0] = m0; red[rg][d4 + 1] = m1; red[rg][d4 + 2] = m2; red[rg][d4 + 3] = m3;
    __syncthreads();
    if (t < 64) {
        float m = -1e30f;
        for (int g = 0; g < 16; g++) m = fmaxf(m, red[g][t]);
        cmx[t] = m;
    }
    __syncthreads();

    float s0 = 0, s1 = 0, s2 = 0, s3 = 0;
    const float c0 = cmx[d4], c1 = cmx[d4 + 1], c2 = cmx[d4 + 2], c3 = cmx[d4 + 3];
    for (int i = 0; i < 16; i++) {
        const int n = n0 + rg + i * 16;
        ushort4 hv = *reinterpret_cast<const ushort4*>(&Km[base + (size_t)n * CC + d4]);
        s0 += __expf(bf2f(hv.x) - c0); s1 += __expf(bf2f(hv.y) - c1);
        s2 += __expf(bf2f(hv.z) - c2); s3 += __expf(bf2f(hv.w) - c3);
    }
    __syncthreads();
    red[rg][d4 + 0] = s0; red[rg][d4 + 1] = s1; red[rg][d4 + 2] = s2; red[rg][d4 + 3] = s3;
    __syncthreads();
    if (t < 64) {
        float tot = 0;
        for (int g = 0; g < 16; g++) tot += red[g][t];
        pmax[((size_t)bh * 16 + ch) * 64 + t] = cmx[t];
        psum[((size_t)bh * 16 + ch) * 64 + t] = tot;
    }
}

// Stage B: combine 16 chunk-partials, normalize in place (bf16).
__global__ __launch_bounds__(256) void ksm_norm_kernel(
    unsigned short* __restrict__ Km, const float* __restrict__ pmax,
    const float* __restrict__ psum)
{
    const int bh = blockIdx.x, ch = blockIdx.y;
    const int b = bh >> 4, h = bh & 15;
    const int t = threadIdx.x;

    __shared__ float cm[64], cinv[64];
    if (t < 64) {
        float m = -1e30f;
        for (int c = 0; c < 16; c++)
            m = fmaxf(m, pmax[((size_t)bh * 16 + c) * 64 + t]);
        float sum = 0;
        for (int c = 0; c < 16; c++)
            sum += psum[((size_t)bh * 16 + c) * 64 + t] *
                   __expf(pmax[((size_t)bh * 16 + c) * 64 + t] - m);
        cm[t] = m;
        cinv[t] = 1.0f / sum;
    }
    __syncthreads();

    const int d4 = (t & 15) * 4, rg = t >> 4;
    const size_t base = (size_t)b * SEQ * CC + (size_t)h * 64;
    const int n0 = ch * 256;
    const float c0 = cm[d4], c1 = cm[d4 + 1], c2 = cm[d4 + 2], c3 = cm[d4 + 3];
    const float i0 = cinv[d4], i1 = cinv[d4 + 1], i2 = cinv[d4 + 2], i3 = cinv[d4 + 3];
    for (int i = 0; i < 16; i++) {
        const int n = n0 + rg + i * 16;
        const size_t o = base + (size_t)n * CC + d4;
        ushort4 hv = *reinterpret_cast<const ushort4*>(&Km[o]);
        ushort4 ov;
        ov.x = f2bf(__expf(bf2f(hv.x) - c0) * i0);
        ov.y = f2bf(__expf(bf2f(hv.y) - c1) * i1);
        ov.z = f2bf(__expf(bf2f(hv.z) - c2) * i2);
        ov.w = f2bf(__expf(bf2f(hv.w) - c3) * i3);
        *reinterpret_cast<ushort4*>(&Km[o]) = ov;
    }
}

// ---------------------------------------------------------------------------
// ctx[bh,d,e] = sum_n Khat[b,n,h,d] * V[b,n,h,e]  (chunked, fp32 atomics)
// ---------------------------------------------------------------------------
__global__ __launch_bounds__(256) void context_kernel(
    const unsigned short* __restrict__ Km, const unsigned short* __restrict__ Vm,
    float* __restrict__ ctx)
{
    const int bh = blockIdx.x, ch = blockIdx.y;
    const int b = bh >> 4, h = bh & 15;
    const int t = threadIdx.x;
    const int d0 = (t >> 4) * 4, e0 = (t & 15) * 4;

    __shared__ float Ks[32][68];
    __shared__ float Vs[32][68];

    float acc[4][4];
#pragma unroll
    for (int i = 0; i < 4; i++)
#pragma unroll
        for (int j = 0; j < 4; j++) acc[i][j] = 0.0f;

    const size_t base = (size_t)(b * SEQ + ch * 256) * CC + (size_t)h * 64;

    for (int n0 = 0; n0 < 256; n0 += 32) {
#pragma unroll
        for (int l = 0; l < 2; l++) {
            const int idx = t + l * 256;
            const int r = idx >> 4, c4 = (idx & 15) * 4;
            ushort4 kv = *reinterpret_cast<const ushort4*>(&Km[base + (size_t)(n0 + r) * CC + c4]);
            ushort4 vv = *reinterpret_cast<const ushort4*>(&Vm[base + (size_t)(n0 + r) * CC + c4]);
            float4 kf = {bf2f(kv.x), bf2f(kv.y), bf2f(kv.z), bf2f(kv.w)};
            float4 vf = {bf2f(vv.x), bf2f(vv.y), bf2f(vv.z), bf2f(vv.w)};
            *reinterpret_cast<float4*>(&Ks[r][c4]) = kf;
            *reinterpret_cast<float4*>(&Vs[r][c4]) = vf;
        }
        __syncthreads();
#pragma unroll 8
        for (int n = 0; n < 32; n++) {
            float4 a = *reinterpret_cast<const float4*>(&Ks[n][d0]);
            float4 v4 = *reinterpret_cast<const float4*>(&Vs[n][e0]);
            float a4[4] = {a.x, a.y, a.z, a.w};
            float b4[4] = {v4.x, v4.y, v4.z, v4.w};
#pragma unroll
            for (int i = 0; i < 4; i++)
#pragma unroll
                for (int j = 0; j < 4; j++)
                    acc[i][j] += a4[i] * b4[j];
        }
        __syncthreads();
    }

#pragma unroll
    for (int i = 0; i < 4; i++)
#pragma unroll
        for (int j = 0; j < 4; j++)
            atomicAdd(&ctx[((size_t)bh * 64 + d0 + i) * 64 + e0 + j], acc[i][j]);
}

// ---------------------------------------------------------------------------
// out2[b,n,h,e] = sum_d Qhat[b,n,h,d] * ctx[bh,d,e] -> bf16 [token, C]
// ---------------------------------------------------------------------------
__global__ __launch_bounds__(256) void attn_out_kernel(
    const unsigned short* __restrict__ Qm, const float* __restrict__ ctx,
    unsigned short* __restrict__ out2)
{
    const int bh = blockIdx.x, nch = blockIdx.y;
    const int b = bh >> 4, h = bh & 15;
    const int t = threadIdx.x;

    __shared__ float Cs[64][68];
    __shared__ float Qs[64][68];

#pragma unroll
    for (int l = 0; l < 4; l++) {
        const int idx = t + l * 256;
        const int r = idx >> 4, c4 = (idx & 15) * 4;
        *reinterpret_cast<float4*>(&Cs[r][c4]) =
            *reinterpret_cast<const float4*>(&ctx[(size_t)bh * 4096 + r * 64 + c4]);
        ushort4 qv = *reinterpret_cast<const ushort4*>(
            &Qm[(size_t)(b * SEQ + nch * 64 + r) * CC + (size_t)h * 64 + c4]);
        float4 qf = {bf2f(qv.x), bf2f(qv.y), bf2f(qv.z), bf2f(qv.w)};
        *reinterpret_cast<float4*>(&Qs[r][c4]) = qf;
    }
    __syncthreads();

    const int r0 = (t >> 4) * 4, e0 = (t & 15) * 4;
    float acc[4][4];
#pragma unroll
    for (int i = 0; i < 4; i++)
#pragma unroll
        for (int j = 0; j < 4; j++) acc[i][j] = 0.0f;

#pragma unroll 8
    for (int d = 0; d < 64; d++) {
        float a4[4];
#pragma unroll
        for (int i = 0; i < 4; i++) a4[i] = Qs[r0 + i][d];
        float4 c4v = *reinterpret_cast<const float4*>(&Cs[d][e0]);
        float b4[4] = {c4v.x, c4v.y, c4v.z, c4v.w};
#pragma unroll
        for (int i = 0; i < 4; i++)
#pragma unroll
            for (int j = 0; j < 4; j++)
                acc[i][j] += a4[i] * b4[j];
    }

#pragma unroll
    for (int i = 0; i < 4; i++) {
        const size_t row = (size_t)(b * SEQ + nch * 64 + r0 + i);
        ushort4 ov;
        ov.x = f2bf(acc[i][0]); ov.y = f2bf(acc[i][1]);
        ov.z = f2bf(acc[i][2]); ov.w = f2bf(acc[i][3]);
        *reinterpret_cast<ushort4*>(&out2[row * CC + h * 64 + e0]) = ov;
    }
}

// ---------------------------------------------------------------------------
extern "C" void kernel_launch(void* const* d_in, const int* in_sizes, int n_in,
                              void* d_out, int out_size, void* d_ws, size_t ws_size,
                              hipStream_t stream)
{
    const float* x      = (const float*)d_in[0];
    const float* W_qkv  = (const float*)d_in[1];
    const float* b_qkv  = (const float*)d_in[2];
    const float* W_proj = (const float*)d_in[3];
    const float* b_proj = (const float*)d_in[4];
    float* out = (float*)d_out;

    // Workspace layout (~144 MB total; round-1 proved >=194 MB available)
    unsigned short* Qm  = (unsigned short*)d_ws;               // [16384,1024] bf16
    unsigned short* Km  = Qm + (size_t)TOKENS * CC;
    unsigned short* Vm  = Km + (size_t)TOKENS * CC;
    unsigned short* xb  = Vm + (size_t)TOKENS * CC;            // x bf16; later aliased by out2
    unsigned short* wqT = xb + (size_t)TOKENS * CC;            // [3072,1024]
    unsigned short* wpT = wqT + (size_t)QKV3 * CC;             // [1024,1024]
    float* ctx  = (float*)(wpT + (size_t)CC * CC);             // [64,64,64] fp32
    float* pmax = ctx + (size_t)64 * 64 * 64;                  // [64,16,64]
    float* psum = pmax + (size_t)64 * 16 * 64;
    unsigned short* out2 = xb;                                  // alias (x dead after QKV GEMM)

    hipMemsetAsync(ctx, 0, (size_t)64 * 64 * 64 * sizeof(float), stream);

    // 0) x -> bf16; weights -> bf16 transposed
    cvt_bf16_kernel<<<(TOKENS * CC / 4 + 255) / 256, 256, 0, stream>>>(
        x, xb, (long)TOKENS * CC / 4);
    transpose_bf16_kernel<<<dim3(QKV3 / 32, CC / 32), 256, 0, stream>>>(
        W_qkv, CC, QKV3, wqT);
    transpose_bf16_kernel<<<dim3(CC / 32, CC / 32), 256, 0, stream>>>(
        W_proj, CC, CC, wpT);

    // 1) QKV GEMM -> Q/K/V bf16 tensors
    gemm_bf16_kernel<1><<<dim3(QKV3 / 128, TOKENS / 128), 256, 0, stream>>>(
        xb, CC, wqT, CC, b_qkv, (float*)nullptr, 0, Qm, Km, Vm, CC);

    // 2) softmax(Q) over head_dim
    q_softmax_kernel<<<(TOKENS * HH) / 16, 256, 0, stream>>>(Qm);

    // 3) softmax(K) over sequence
    ksm_partial_kernel<<<dim3(BBATCH * HH, 16), 256, 0, stream>>>(Km, pmax, psum);
    ksm_norm_kernel<<<dim3(BBATCH * HH, 16), 256, 0, stream>>>(Km, pmax, psum);

    // 4) ctx = Khat^T V per head
    context_kernel<<<dim3(BBATCH * HH, 16), 256, 0, stream>>>(Km, Vm, ctx);

    // 5) out2 = Qhat @ ctx -> bf16
    attn_out_kernel<<<dim3(BBATCH * HH, SEQ / 64), 256, 0, stream>>>(Qm, ctx, out2);

    // 6) proj GEMM -> fp32 out
    gemm_bf16_kernel<0><<<dim3(CC / 128, TOKENS / 128), 256, 0, stream>>>(
        out2, CC, wpT, CC, b_proj, out, CC, nullptr, nullptr, nullptr, CC);
}